// Round 1
// baseline (515.494 us; speedup 1.0000x reference)
//
#include <hip/hip_runtime.h>
#include <hip/hip_bf16.h>
#include <cstdint>
#include <cstddef>

#define S_LEN 2048
#define DM 1024
#define NEGV -1.0e9f

typedef __attribute__((ext_vector_type(8))) short bf16x8;
typedef __attribute__((ext_vector_type(4))) float f32x4;
typedef __attribute__((ext_vector_type(4))) unsigned short us4;

__device__ __forceinline__ unsigned short f2bf(float f) {
  unsigned int u = __float_as_uint(f);
  unsigned int r = (u + 0x7fffu + ((u >> 16) & 1u)) >> 16;
  return (unsigned short)r;
}

__device__ __forceinline__ void async_copy16(const void* g, void* l) {
  __builtin_amdgcn_global_load_lds((const __attribute__((address_space(1))) void*)g,
                                   (__attribute__((address_space(3))) void*)l, 16, 0, 0);
}

// ---------------- f32 -> bf16 convert ----------------
__global__ void cvt_kernel(const float* __restrict__ src, unsigned short* __restrict__ dst, int n4) {
  int i = blockIdx.x * blockDim.x + threadIdx.x;
  if (i >= n4) return;
  const float4 v = reinterpret_cast<const float4*>(src)[i];
  us4 o;
  o[0] = f2bf(v.x); o[1] = f2bf(v.y); o[2] = f2bf(v.z); o[3] = f2bf(v.w);
  reinterpret_cast<us4*>(dst)[i] = o;
}

// ---------------- projection GEMM: C[m,n] = sum_k X[m,k] W[n,k] + bias[n] ----------------
// X: [4096,1024] bf16 row-major, W: [1024,1024] bf16 row-major (nn.Linear weight [out,in])
// tile 128x128, BK=64, 256 threads (4 waves, 2x2 of 64x64), 16x16x32 bf16 MFMA
__global__ __launch_bounds__(256) void proj_gemm(
    const unsigned short* __restrict__ Xq, const unsigned short* __restrict__ Wqw,
    const float* __restrict__ bq, unsigned short* __restrict__ Cq,
    const unsigned short* __restrict__ Xk, const unsigned short* __restrict__ Wkw,
    const float* __restrict__ bk, unsigned short* __restrict__ Ck,
    const unsigned short* __restrict__ Xv, const unsigned short* __restrict__ Wvw,
    const float* __restrict__ bv, unsigned short* __restrict__ Cv) {
  const unsigned short* X; const unsigned short* W; const float* bias; unsigned short* C;
  if (blockIdx.z == 0)      { X = Xq; W = Wqw; bias = bq; C = Cq; }
  else if (blockIdx.z == 1) { X = Xk; W = Wkw; bias = bk; C = Ck; }
  else                      { X = Xv; W = Wvw; bias = bv; C = Cv; }

  __shared__ unsigned short Ab[128 * 64];
  __shared__ unsigned short Bb[128 * 64];

  const int t  = threadIdx.x;
  const int wv = t >> 6, l = t & 63;
  const int lr = l & 15, lg = l >> 4;
  const int wr = wv >> 1, wc = wv & 1;
  const int m0 = blockIdx.y * 128, n0 = blockIdx.x * 128;

  const f32x4 fz = {0.f, 0.f, 0.f, 0.f};
  f32x4 acc[4][4];
#pragma unroll
  for (int m = 0; m < 4; ++m)
#pragma unroll
    for (int n = 0; n < 4; ++n) acc[m][n] = fz;

  const int srow = t >> 3;  // 0..31
  const int sc16 = t & 7;

  for (int kt = 0; kt < 16; ++kt) {
    const int kb = kt * 64;
#pragma unroll
    for (int it = 0; it < 4; ++it) {
      const int row = it * 32 + srow;
      const int c16 = sc16 ^ (row & 7);  // pre-swizzled global source (LDS dest stays linear)
      const unsigned short* gA = X + (size_t)(m0 + row) * DM + kb + c16 * 8;
      const unsigned short* gB = W + (size_t)(n0 + row) * DM + kb + c16 * 8;
      async_copy16(gA, (char*)Ab + it * 4096 + wv * 1024);
      async_copy16(gB, (char*)Bb + it * 4096 + wv * 1024);
    }
    __syncthreads();
#pragma unroll
    for (int kk = 0; kk < 2; ++kk) {
      bf16x8 af[4], bfr[4];
      const int c16 = kk * 4 + lg;
      const int sw = (c16 ^ (lr & 7)) * 16;
#pragma unroll
      for (int m = 0; m < 4; ++m) {
        const int row = wr * 64 + m * 16 + lr;
        af[m] = *(const bf16x8*)((const char*)Ab + row * 128 + sw);
      }
#pragma unroll
      for (int n = 0; n < 4; ++n) {
        const int row = wc * 64 + n * 16 + lr;
        bfr[n] = *(const bf16x8*)((const char*)Bb + row * 128 + sw);
      }
#pragma unroll
      for (int m = 0; m < 4; ++m)
#pragma unroll
        for (int n = 0; n < 4; ++n)
          acc[m][n] = __builtin_amdgcn_mfma_f32_16x16x32_bf16(af[m], bfr[n], acc[m][n], 0, 0, 0);
    }
    __syncthreads();
  }

#pragma unroll
  for (int n = 0; n < 4; ++n) {
    const int ccol = n0 + wc * 64 + n * 16 + lr;
    const float bb = bias[ccol];
#pragma unroll
    for (int m = 0; m < 4; ++m) {
      const int crow0 = m0 + wr * 64 + m * 16 + lg * 4;
#pragma unroll
      for (int j = 0; j < 4; ++j)
        C[(size_t)(crow0 + j) * DM + ccol] = f2bf(acc[m][n][j] + bb);
    }
  }
}

// ---------------- V transpose: Vt[n][m] = Vp[m][n], [4096,1024] -> [1024,4096] ----------------
__global__ void transpose_bf(const unsigned short* __restrict__ src, unsigned short* __restrict__ dst) {
  __shared__ unsigned short tb[32][33];
  const int x = threadIdx.x & 31, y = threadIdx.x >> 5;
  const int bx = blockIdx.x, by = blockIdx.y;
#pragma unroll
  for (int r = 0; r < 32; r += 8)
    tb[r + y][x] = src[(size_t)(by * 32 + r + y) * DM + bx * 32 + x];
  __syncthreads();
#pragma unroll
  for (int r = 0; r < 32; r += 8)
    dst[(size_t)(bx * 32 + r + y) * 4096 + by * 32 + x] = tb[x][r + y];
}

// ---------------- fused attention ----------------
// block: 16 query rows, 1024 threads = 16 waves; wave w owns key cols [w*128, w*128+128)
// scores stay in registers (8 C-frags/wave); softmax via xor-shuffle + LDS cross-wave reduce;
// attn weights written once (f32, coalesced); P repacked to padded LDS for PV MFMA.
__global__ __launch_bounds__(1024) void attn_kernel(
    const unsigned short* __restrict__ Qp, const unsigned short* __restrict__ Kp,
    const unsigned short* __restrict__ Vt, const int* __restrict__ mask,
    float* __restrict__ outp, float* __restrict__ attnp) {
  __shared__ unsigned short P_lds[16 * 2056];  // 65792 B (pad 8 bf16 per row -> 2-way-free reads)
  __shared__ float redmax[16][16];
  __shared__ float redsum[16][16];

  const int tid = threadIdx.x;
  const int w = tid >> 6, l = tid & 63;
  const int lr = l & 15, lg = l >> 4;
  const int qt = blockIdx.x, bh = blockIdx.y;
  const int b = bh >> 4, h = bh & 15;
  const int q0 = qt * 16;

  const unsigned short* Qh = Qp + (size_t)b * S_LEN * DM + h * 64;
  const unsigned short* Kh = Kp + (size_t)b * S_LEN * DM + h * 64;

  const bf16x8 qa0 = *(const bf16x8*)(Qh + (size_t)(q0 + lr) * DM + lg * 8);
  const bf16x8 qa1 = *(const bf16x8*)(Qh + (size_t)(q0 + lr) * DM + 32 + lg * 8);

  const f32x4 fz = {0.f, 0.f, 0.f, 0.f};
  f32x4 sc[8];
#pragma unroll
  for (int nb = 0; nb < 8; ++nb) sc[nb] = fz;

#pragma unroll
  for (int nb = 0; nb < 8; ++nb) {
    const int kcol = w * 128 + nb * 16 + lr;
    const bf16x8 kb0 = *(const bf16x8*)(Kh + (size_t)kcol * DM + lg * 8);
    const bf16x8 kb1 = *(const bf16x8*)(Kh + (size_t)kcol * DM + 32 + lg * 8);
    sc[nb] = __builtin_amdgcn_mfma_f32_16x16x32_bf16(qa0, kb0, sc[nb], 0, 0, 0);
    sc[nb] = __builtin_amdgcn_mfma_f32_16x16x32_bf16(qa1, kb1, sc[nb], 0, 0, 0);
  }

  // mask + scale + row max (C-frag: col = lr (+16*nb +128*w), row = lg*4 + j)
  const float scale = 0.125f;
  float rmax[4] = {-3e38f, -3e38f, -3e38f, -3e38f};
#pragma unroll
  for (int nb = 0; nb < 8; ++nb) {
    const int col = w * 128 + nb * 16 + lr;
    const int* mptr = mask + ((size_t)b * S_LEN + q0 + lg * 4) * S_LEN + col;
#pragma unroll
    for (int j = 0; j < 4; ++j) {
      const int mk = mptr[(size_t)j * S_LEN];
      const float sv = (mk == 0) ? NEGV : sc[nb][j] * scale;
      sc[nb][j] = sv;
      rmax[j] = fmaxf(rmax[j], sv);
    }
  }
#pragma unroll
  for (int j = 0; j < 4; ++j)
#pragma unroll
    for (int off = 8; off >= 1; off >>= 1)
      rmax[j] = fmaxf(rmax[j], __shfl_xor(rmax[j], off, 64));
  if (lr == 0) {
#pragma unroll
    for (int j = 0; j < 4; ++j) redmax[w][lg * 4 + j] = rmax[j];
  }
  __syncthreads();
  float mfin[4];
#pragma unroll
  for (int j = 0; j < 4; ++j) {
    float mm = redmax[0][lg * 4 + j];
#pragma unroll
    for (int ww = 1; ww < 16; ++ww) mm = fmaxf(mm, redmax[ww][lg * 4 + j]);
    mfin[j] = mm;
  }
  float rs[4] = {0.f, 0.f, 0.f, 0.f};
#pragma unroll
  for (int nb = 0; nb < 8; ++nb)
#pragma unroll
    for (int j = 0; j < 4; ++j) {
      const float p = __expf(sc[nb][j] - mfin[j]);
      sc[nb][j] = p;
      rs[j] += p;
    }
#pragma unroll
  for (int j = 0; j < 4; ++j)
#pragma unroll
    for (int off = 8; off >= 1; off >>= 1)
      rs[j] += __shfl_xor(rs[j], off, 64);
  if (lr == 0) {
#pragma unroll
    for (int j = 0; j < 4; ++j) redsum[w][lg * 4 + j] = rs[j];
  }
  __syncthreads();
  float rinv[4];
#pragma unroll
  for (int j = 0; j < 4; ++j) {
    float ssum = 0.f;
#pragma unroll
    for (int ww = 0; ww < 16; ++ww) ssum += redsum[ww][lg * 4 + j];
    rinv[j] = 1.0f / ssum;
  }

  // write normalized attn (f32) + stash bf16 P in LDS for PV
  float* attnrow = attnp + ((size_t)bh * S_LEN + q0) * S_LEN;
#pragma unroll
  for (int nb = 0; nb < 8; ++nb) {
    const int col = w * 128 + nb * 16 + lr;
#pragma unroll
    for (int j = 0; j < 4; ++j) {
      const int row = lg * 4 + j;
      const float p = sc[nb][j] * rinv[j];
      attnrow[(size_t)row * S_LEN + col] = p;
      P_lds[row * 2056 + col] = f2bf(p);
    }
  }
  __syncthreads();

  // PV: out_partial[16 q][64 d] over this wave's 128-key slice
  f32x4 oacc[4];
#pragma unroll
  for (int n = 0; n < 4; ++n) oacc[n] = fz;
  const unsigned short* Vh = Vt + (size_t)h * 64 * 4096 + (size_t)b * S_LEN;
#pragma unroll
  for (int kk2 = 0; kk2 < 4; ++kk2) {
    const int kb = w * 128 + kk2 * 32;
    const bf16x8 pa = *(const bf16x8*)(&P_lds[lr * 2056 + kb + lg * 8]);
#pragma unroll
    for (int n = 0; n < 4; ++n) {
      const bf16x8 vb = *(const bf16x8*)(Vh + (size_t)(n * 16 + lr) * 4096 + kb + lg * 8);
      oacc[n] = __builtin_amdgcn_mfma_f32_16x16x32_bf16(pa, vb, oacc[n], 0, 0, 0);
    }
  }
  __syncthreads();  // all waves done reading P_lds

  // cross-wave reduction of out through LDS (reuse P_lds region as f32 buffer)
  float* redF = (float*)P_lds;  // need 16*16*64*4 = 65536 B <= 65792 B
#pragma unroll
  for (int n = 0; n < 4; ++n)
#pragma unroll
    for (int j = 0; j < 4; ++j)
      redF[(w * 16 + lg * 4 + j) * 64 + n * 16 + lr] = oacc[n][j];
  __syncthreads();
  {
    const int q = tid >> 6, d = tid & 63;
    float ssum = 0.f;
#pragma unroll
    for (int ww = 0; ww < 16; ++ww) ssum += redF[(ww * 16 + q) * 64 + d];
    outp[((size_t)b * S_LEN + q0 + q) * DM + h * 64 + d] = ssum;
  }
}

extern "C" void kernel_launch(void* const* d_in, const int* in_sizes, int n_in,
                              void* d_out, int out_size, void* d_ws, size_t ws_size,
                              hipStream_t stream) {
  const float* query = (const float*)d_in[0];
  const float* key_  = (const float*)d_in[1];
  const float* value = (const float*)d_in[2];
  const int*   mask  = (const int*)d_in[3];
  const float* Wq = (const float*)d_in[4];
  const float* bq = (const float*)d_in[5];
  const float* Wk = (const float*)d_in[6];
  const float* bk = (const float*)d_in[7];
  const float* Wv = (const float*)d_in[8];
  const float* bv = (const float*)d_in[9];

  float* outp  = (float*)d_out;
  float* attnp = outp + (size_t)2 * S_LEN * DM;

  unsigned short* ws  = (unsigned short*)d_ws;
  unsigned short* qbf = ws;
  unsigned short* kbf = qbf + 4194304;
  unsigned short* vbf = kbf + 4194304;
  unsigned short* wqb = vbf + 4194304;
  unsigned short* wkb = wqb + 1048576;
  unsigned short* wvb = wkb + 1048576;
  unsigned short* qp  = wvb + 1048576;
  unsigned short* kp  = qp + 4194304;
  unsigned short* vp  = kp + 4194304;
  unsigned short* vt  = vp + 4194304;

  cvt_kernel<<<4096, 256, 0, stream>>>(query, qbf, 1048576);
  cvt_kernel<<<4096, 256, 0, stream>>>(key_,  kbf, 1048576);
  cvt_kernel<<<4096, 256, 0, stream>>>(value, vbf, 1048576);
  cvt_kernel<<<1024, 256, 0, stream>>>(Wq, wqb, 262144);
  cvt_kernel<<<1024, 256, 0, stream>>>(Wk, wkb, 262144);
  cvt_kernel<<<1024, 256, 0, stream>>>(Wv, wvb, 262144);

  proj_gemm<<<dim3(8, 32, 3), 256, 0, stream>>>(qbf, wqb, bq, qp,
                                                kbf, wkb, bk, kp,
                                                vbf, wvb, bv, vp);
  transpose_bf<<<dim3(32, 128), 256, 0, stream>>>(vp, vt);
  attn_kernel<<<dim3(128, 32), 1024, 0, stream>>>(qp, kp, vt, mask, outp, attnp);
}